// Round 1
// baseline (43.286 us; speedup 1.0000x reference)
//
#include <hip/hip_runtime.h>

// out[b] = Q[b] @ (K[b]^T @ V[b]) / 8      (softmax in ref is dead code)
// B=8, S=2048, D=128, fp32 in/out.

#define B 8
#define S 2048
#define D 128

// ---------------- Stage 1: P[b][c] = K_chunk^T @ V_chunk (128x128) ----------
__global__ __launch_bounds__(256) void kt_v_partial(
    const float* __restrict__ K, const float* __restrict__ V,
    float* __restrict__ P, int schunk, int nchunk)
{
    int b = blockIdx.x / nchunk;
    int c = blockIdx.x % nchunk;
    const float* Kb = K + (size_t)b * S * D + (size_t)c * schunk * D;
    const float* Vb = V + (size_t)b * S * D + (size_t)c * schunk * D;
    float* Pout = P + (size_t)blockIdx.x * D * D;

    __shared__ float Ks[64][D];
    __shared__ float Vs[64][D];

    int tid = threadIdx.x;
    int tx = tid & 15, ty = tid >> 4;   // 16x16 threads, 8x8 tile each

    float acc[8][8];
#pragma unroll
    for (int i = 0; i < 8; i++)
#pragma unroll
        for (int j = 0; j < 8; j++) acc[i][j] = 0.f;

    for (int s0 = 0; s0 < schunk; s0 += 64) {
        // load 64 rows of K and V: 2048 float4 each, 8 float4/thread
#pragma unroll
        for (int it = 0; it < 8; ++it) {
            int idx = it * 256 + tid;       // float4 index
            int row = idx >> 5;             // 32 float4 per row
            int col = (idx & 31) * 4;
            *(float4*)&Ks[row][col] = *(const float4*)&Kb[(size_t)(s0 + row) * D + col];
            *(float4*)&Vs[row][col] = *(const float4*)&Vb[(size_t)(s0 + row) * D + col];
        }
        __syncthreads();

        for (int s = 0; s < 64; ++s) {
            float k[8], v[8];
#pragma unroll
            for (int i = 0; i < 8; i++) k[i] = Ks[s][ty * 8 + i];
#pragma unroll
            for (int j = 0; j < 8; j++) v[j] = Vs[s][tx * 8 + j];
#pragma unroll
            for (int i = 0; i < 8; i++)
#pragma unroll
                for (int j = 0; j < 8; j++)
                    acc[i][j] = fmaf(k[i], v[j], acc[i][j]);
        }
        __syncthreads();
    }

#pragma unroll
    for (int i = 0; i < 8; i++) {
#pragma unroll
        for (int j = 0; j < 8; j += 4) {
            float4 t = { acc[i][j], acc[i][j + 1], acc[i][j + 2], acc[i][j + 3] };
            *(float4*)&Pout[(size_t)(ty * 8 + i) * D + tx * 8 + j] = t;
        }
    }
}

// ---------------- Stage 2: M[b] = (1/8) * sum_c P[b][c] ---------------------
__global__ __launch_bounds__(256) void reduce_p(
    const float* __restrict__ P, float* __restrict__ M, int nchunk)
{
    int idx = blockIdx.x * 256 + threadIdx.x;  // over B*D*D = 131072
    int b = idx >> 14;          // D*D = 16384
    int i = idx & 16383;
    float s = 0.f;
    for (int c = 0; c < nchunk; ++c)
        s += P[((size_t)(b * nchunk + c) << 14) + i];
    M[idx] = s * 0.125f;
}

// ---------------- Stage 3: Out[b] = Q[b] @ M[b] ------------------------------
__global__ __launch_bounds__(256) void q_m(
    const float* __restrict__ Q, const float* __restrict__ M,
    float* __restrict__ Out)
{
    const int nrb = S / 64;                 // 32 row-blocks per batch
    int b = blockIdx.x / nrb;
    int rb = blockIdx.x % nrb;
    const float* Qb = Q + (size_t)b * S * D + (size_t)rb * 64 * D;
    const float* Mb = M + (size_t)b * D * D;
    float* Ob = Out + (size_t)b * S * D + (size_t)rb * 64 * D;

    __shared__ float Qs[64][D];             // 32 KB
    __shared__ float Ms[D][D];              // 64 KB

    int tid = threadIdx.x;
#pragma unroll
    for (int it = 0; it < 8; ++it) {        // Q tile: 2048 float4
        int idx = it * 256 + tid;
        int row = idx >> 5; int col = (idx & 31) * 4;
        *(float4*)&Qs[row][col] = *(const float4*)&Qb[(size_t)row * D + col];
    }
#pragma unroll
    for (int it = 0; it < 16; ++it) {       // M: 4096 float4
        int idx = it * 256 + tid;
        int row = idx >> 5; int col = (idx & 31) * 4;
        *(float4*)&Ms[row][col] = *(const float4*)&Mb[(size_t)row * D + col];
    }
    __syncthreads();

    int tx = tid & 15, ty = tid >> 4;       // rows ty*4..+4, cols tx*8..+8
    float acc[4][8];
#pragma unroll
    for (int i = 0; i < 4; i++)
#pragma unroll
        for (int j = 0; j < 8; j++) acc[i][j] = 0.f;

    for (int k = 0; k < D; ++k) {
        float q[4], m[8];
#pragma unroll
        for (int i = 0; i < 4; i++) q[i] = Qs[ty * 4 + i][k];
#pragma unroll
        for (int j = 0; j < 8; j++) m[j] = Ms[k][tx * 8 + j];
#pragma unroll
        for (int i = 0; i < 4; i++)
#pragma unroll
            for (int j = 0; j < 8; j++)
                acc[i][j] = fmaf(q[i], m[j], acc[i][j]);
    }

#pragma unroll
    for (int i = 0; i < 4; i++) {
#pragma unroll
        for (int j = 0; j < 8; j += 4) {
            float4 t = { acc[i][j], acc[i][j + 1], acc[i][j + 2], acc[i][j + 3] };
            *(float4*)&Ob[(size_t)(ty * 4 + i) * D + tx * 8 + j] = t;
        }
    }
}

extern "C" void kernel_launch(void* const* d_in, const int* in_sizes, int n_in,
                              void* d_out, int out_size, void* d_ws, size_t ws_size,
                              hipStream_t stream)
{
    const float* q = (const float*)d_in[0];
    const float* k = (const float*)d_in[1];
    const float* v = (const float*)d_in[2];
    float* out = (float*)d_out;

    const size_t Mbytes = (size_t)B * D * D * sizeof(float);   // 512 KB
    int CH = 32;
    while (CH > 1 && (size_t)B * CH * D * D * sizeof(float) + Mbytes > ws_size)
        CH >>= 1;
    int schunk = S / CH;

    float* P = (float*)d_ws;
    float* M = (float*)((char*)d_ws + (size_t)B * CH * D * D * sizeof(float));

    kt_v_partial<<<B * CH, 256, 0, stream>>>(k, v, P, schunk, CH);
    reduce_p<<<(B * D * D) / 256, 256, 0, stream>>>(P, M, CH);
    q_m<<<B * (S / 64), 256, 0, stream>>>(q, M, out);
}

// Round 2
// 23.446 us; speedup vs baseline: 1.8462x; 1.8462x over previous
//
#include <hip/hip_runtime.h>

// out[b] = Q[b] @ (K[b]^T @ V[b]) / 8      (softmax in ref is dead code)
// B=8, S=2048, D=128, fp32 in/out. MFMA bf16 pipeline, no LDS.

#define B 8
#define S 2048
#define D 128
#define CH 32          // s-chunks per batch in stage 1
#define SC 64          // rows per chunk (S / CH)

typedef __attribute__((ext_vector_type(8))) short short8;
typedef __attribute__((ext_vector_type(4))) float f32x4;

static __device__ __forceinline__ short f2bf(float f) {
    union { float f; unsigned u; } x; x.f = f;
    unsigned r = x.u + 0x7FFF + ((x.u >> 16) & 1);   // RNE
    return (short)(r >> 16);
}
static __device__ __forceinline__ float bf2f(unsigned short s) {
    union { unsigned u; float f; } x; x.u = ((unsigned)s) << 16;
    return x.f;
}

// ---- Stage 1: P[b][c] (bf16) = K_chunk^T @ V_chunk, per 64-row chunk -------
__global__ __launch_bounds__(256) void s1_ktv(
    const float* __restrict__ K, const float* __restrict__ V,
    unsigned short* __restrict__ P)
{
    int blk = blockIdx.x;
    int b = blk >> 5, ch = blk & 31;
    const float* Kb = K + (size_t)b * S * D + (size_t)ch * SC * D;
    const float* Vb = V + (size_t)b * S * D + (size_t)ch * SC * D;

    int tid = threadIdx.x;
    int w = tid >> 6, l = tid & 63;
    int lr = l & 15, lg = l >> 4;
    int dr0 = (w >> 1) * 64;        // output row quadrant (d)
    int cc0 = (w & 1) * 64;         // output col quadrant (c)

    f32x4 acc[4][4];
#pragma unroll
    for (int i = 0; i < 4; i++)
#pragma unroll
        for (int j = 0; j < 4; j++) acc[i][j] = (f32x4)0.f;

#pragma unroll
    for (int ks = 0; ks < 2; ++ks) {
        int sb = ks * 32 + lg * 8;          // this lane's 8 s-rows
        short8 af[4], bv[4];
#pragma unroll
        for (int fi = 0; fi < 4; ++fi) {    // A = K^T rows (= K columns)
            const float* kp = Kb + (size_t)sb * D + dr0 + fi * 16 + lr;
            short8 t;
#pragma unroll
            for (int i = 0; i < 8; ++i) t[i] = f2bf(kp[(size_t)i * D]);
            af[fi] = t;
        }
#pragma unroll
        for (int fj = 0; fj < 4; ++fj) {    // B = V columns
            const float* vp = Vb + (size_t)sb * D + cc0 + fj * 16 + lr;
            short8 t;
#pragma unroll
            for (int i = 0; i < 8; ++i) t[i] = f2bf(vp[(size_t)i * D]);
            bv[fj] = t;
        }
#pragma unroll
        for (int fi = 0; fi < 4; ++fi)
#pragma unroll
            for (int fj = 0; fj < 4; ++fj)
                acc[fi][fj] = __builtin_amdgcn_mfma_f32_16x16x32_bf16(
                    af[fi], bv[fj], acc[fi][fj], 0, 0, 0);
    }

    unsigned short* Pb = P + (size_t)blk * D * D;
#pragma unroll
    for (int fi = 0; fi < 4; ++fi)
#pragma unroll
        for (int fj = 0; fj < 4; ++fj)
#pragma unroll
            for (int j = 0; j < 4; ++j) {
                int row = dr0 + fi * 16 + lg * 4 + j;
                int col = cc0 + fj * 16 + lr;
                Pb[row * D + col] = (unsigned short)f2bf(acc[fi][fj][j]);
            }
}

// ---- Stage 2: MT[b][c][k] (bf16) = (1/8) * sum_cc P[b][cc][k][c] ----------
__global__ __launch_bounds__(256) void s2_reduce(
    const unsigned short* __restrict__ P, unsigned short* __restrict__ MT)
{
    int idx = blockIdx.x * 256 + threadIdx.x;   // 65536 threads, 2 elems each
    int i0 = idx * 2;
    int b = i0 >> 14;
    int r = i0 & 16383;                          // r = k*128 + c, c even
    const unsigned short* Pb = P + ((size_t)b * CH) * D * D;
    float s0 = 0.f, s1 = 0.f;
#pragma unroll
    for (int cc = 0; cc < CH; ++cc) {
        unsigned pair = *(const unsigned*)(Pb + (size_t)cc * D * D + r);
        s0 += bf2f((unsigned short)(pair & 0xFFFF));
        s1 += bf2f((unsigned short)(pair >> 16));
    }
    int k = r >> 7, c = r & 127;
    unsigned short* Mb = MT + (size_t)b * D * D;
    Mb[c * D + k]       = (unsigned short)f2bf(s0 * 0.125f);
    Mb[(c + 1) * D + k] = (unsigned short)f2bf(s1 * 0.125f);
}

// ---- Stage 3: out[b] = Q[b] @ M[b]  (B-operand from MT, contiguous k) ------
__global__ __launch_bounds__(256) void s3_qm(
    const float* __restrict__ Q, const unsigned short* __restrict__ MT,
    float* __restrict__ Out)
{
    int blk = blockIdx.x;
    int b = blk >> 5, rc = blk & 31;
    int tid = threadIdx.x;
    int w = tid >> 6, l = tid & 63;
    int lr = l & 15, lg = l >> 4;
    int r0 = rc * 64 + w * 16;                   // 16 rows per wave

    const float* Qb = Q + (size_t)b * S * D + (size_t)r0 * D;
    const unsigned short* Mb = MT + (size_t)b * D * D;

    f32x4 acc[8];
#pragma unroll
    for (int j = 0; j < 8; j++) acc[j] = (f32x4)0.f;

#pragma unroll
    for (int ks = 0; ks < 4; ++ks) {
        int k0 = ks * 32 + lg * 8;
        const float* qp = Qb + (size_t)lr * D + k0;
        float4 q0 = *(const float4*)qp;
        float4 q1 = *(const float4*)(qp + 4);
        short8 a;
        a[0] = f2bf(q0.x); a[1] = f2bf(q0.y); a[2] = f2bf(q0.z); a[3] = f2bf(q0.w);
        a[4] = f2bf(q1.x); a[5] = f2bf(q1.y); a[6] = f2bf(q1.z); a[7] = f2bf(q1.w);
#pragma unroll
        for (int fj = 0; fj < 8; ++fj) {
            short8 bb = *(const short8*)(Mb + (size_t)(fj * 16 + lr) * D + k0);
            acc[fj] = __builtin_amdgcn_mfma_f32_16x16x32_bf16(a, bb, acc[fj], 0, 0, 0);
        }
    }

    float* Ob = Out + (size_t)b * S * D + (size_t)r0 * D;
#pragma unroll
    for (int fj = 0; fj < 8; ++fj)
#pragma unroll
        for (int j = 0; j < 4; ++j)
            Ob[(size_t)(lg * 4 + j) * D + fj * 16 + lr] = acc[fj][j];
}

extern "C" void kernel_launch(void* const* d_in, const int* in_sizes, int n_in,
                              void* d_out, int out_size, void* d_ws, size_t ws_size,
                              hipStream_t stream)
{
    const float* q = (const float*)d_in[0];
    const float* k = (const float*)d_in[1];
    const float* v = (const float*)d_in[2];
    float* out = (float*)d_out;

    unsigned short* P  = (unsigned short*)d_ws;                       // 8.4 MB
    unsigned short* MT = P + (size_t)B * CH * D * D;                  // 256 KB

    s1_ktv<<<B * CH, 256, 0, stream>>>(k, v, P);
    s2_reduce<<<(B * D * D / 2) / 256, 256, 0, stream>>>(P, MT);
    s3_qm<<<B * CH, 256, 0, stream>>>(q, MT, out);
}